// Round 3
// baseline (1169.449 us; speedup 1.0000x reference)
//
#include <hip/hip_runtime.h>

// LMFreezeConcatModel: lm = X@W_lm+b ; 3x GCNConv(sym-norm, self-loops) ; concat -> W_cls.
// R3: R2 with compile fix (cvt_pkrtz returns __fp16-based vector type).

typedef unsigned short u16;
typedef unsigned int   u32;
typedef _Float16 f16;
typedef f16 f16x8 __attribute__((ext_vector_type(8)));
typedef f16 f16x2 __attribute__((ext_vector_type(2)));
typedef __fp16 fp16x2_storage __attribute__((ext_vector_type(2)));
typedef float f32x4 __attribute__((ext_vector_type(4)));

__device__ __forceinline__ u32 pkh2(float a, float b) {
  fp16x2_storage h = __builtin_amdgcn_cvt_pkrtz(a, b);   // v_cvt_pkrtz_f16_f32, 1 instr
  return __builtin_bit_cast(u32, h);
}
__device__ __forceinline__ float h2f_lo(u32 u) { return (float)__builtin_bit_cast(f16x2, u)[0]; }
__device__ __forceinline__ float h2f_hi(u32 u) { return (float)__builtin_bit_cast(f16x2, u)[1]; }
__device__ __forceinline__ u16 f2h(float f) { return __builtin_bit_cast(u16, (f16)f); }

// ---------------- degree / CSR build ----------------

__global__ void count_kernel(const int* __restrict__ dst, int* __restrict__ counts, int E) {
  int e = blockIdx.x * 256 + threadIdx.x;
  if (e < E) atomicAdd(&counts[dst[e]], 1);
}

__global__ void dinv_kernel(const int* __restrict__ counts, float* __restrict__ dinv, int N) {
  int i = blockIdx.x * 256 + threadIdx.x;
  if (i < N) dinv[i] = rsqrtf((float)(counts[i] + 1));   // +1 self-loop
}

__global__ void scan_partial(const int* __restrict__ counts, int* __restrict__ partials, int N) {
  __shared__ int sdata[256];
  int t = threadIdx.x;
  int base = blockIdx.x * 1024 + t * 4;
  int s = 0;
#pragma unroll
  for (int i = 0; i < 4; i++) { int idx = base + i; if (idx < N) s += counts[idx]; }
  sdata[t] = s; __syncthreads();
  for (int off = 128; off > 0; off >>= 1) {
    if (t < off) sdata[t] += sdata[t + off];
    __syncthreads();
  }
  if (t == 0) partials[blockIdx.x] = sdata[0];
}

__global__ void scan_partials_excl(int* __restrict__ partials, int NB,
                                   int* __restrict__ offsets, int N, int E) {
  __shared__ int sdata[256];
  int t = threadIdx.x;
  int v = (t < NB) ? partials[t] : 0;
  sdata[t] = v; __syncthreads();
  int val = v;
  for (int off = 1; off < 256; off <<= 1) {
    int add = (t >= off) ? sdata[t - off] : 0;
    __syncthreads();
    val += add; sdata[t] = val;
    __syncthreads();
  }
  if (t < NB) partials[t] = val - v;
  if (t == 0) offsets[N] = E;
}

__global__ void scan_final(const int* __restrict__ counts, const int* __restrict__ partials,
                           int* __restrict__ offsets, int N) {
  __shared__ int sdata[256];
  int t = threadIdx.x;
  int base = blockIdx.x * 1024 + t * 4;
  int v[4]; int tsum = 0;
#pragma unroll
  for (int i = 0; i < 4; i++) { int idx = base + i; v[i] = (idx < N) ? counts[idx] : 0; tsum += v[i]; }
  sdata[t] = tsum; __syncthreads();
  int val = tsum;
  for (int off = 1; off < 256; off <<= 1) {
    int add = (t >= off) ? sdata[t - off] : 0;
    __syncthreads();
    val += add; sdata[t] = val;
    __syncthreads();
  }
  int run = partials[blockIdx.x] + val - tsum;
#pragma unroll
  for (int i = 0; i < 4; i++) { int idx = base + i; if (idx < N) offsets[idx] = run; run += v[i]; }
}

__global__ void fill_kernel(const int* __restrict__ src, const int* __restrict__ dst,
                            const int* __restrict__ offsets, int* __restrict__ cursor,
                            const float* __restrict__ dinv,
                            int* __restrict__ col, float* __restrict__ wn, int E) {
  int e = blockIdx.x * 256 + threadIdx.x;
  if (e < E) {
    int d = dst[e], s = src[e];
    int p = offsets[d] + atomicAdd(&cursor[d], 1);
    col[p] = s;
    wn[p] = dinv[s] * dinv[d];
  }
}

// ---------------- weight prep: f32 -> f16, transposed to [col][k] ----------------

__global__ void prep_weights(const float* __restrict__ Wlm, const float* __restrict__ Wg,
                             f16* __restrict__ WlmT, f16* __restrict__ WgT, int total) {
  int idx = blockIdx.x * 256 + threadIdx.x;
  if (idx < 1024 * 128) {
    int k = idx >> 7, c = idx & 127;
    WlmT[c * 1024 + k] = (f16)Wlm[idx];
  } else if (idx < total) {
    int r = idx - 1024 * 128;
    int l = r >> 14; int rr = r & 16383;
    int k = rr >> 7, c = rr & 127;
    WgT[l * 16384 + c * 128 + k] = (f16)Wg[r];
  }
}

// ---------------- lm GEMM: Out[N][128] = f16(X[N][1024]) @ W + b ----------------
// BM=128, BN=128, BK=32, 4 waves (wave tile 64x64). A staged f32->f16 via pkrtz; B frags from global.

template<int K>
__global__ __launch_bounds__(256) void lm_gemm_kernel(
    const float* __restrict__ A, const f16* __restrict__ Bt,   // Bt[128][K]
    const float* __restrict__ bias, u16* __restrict__ Out, int Nrows)
{
  __shared__ u16 lA[128 * 32];
  const int t = threadIdx.x;
  const int lane = t & 63;
  const int w = t >> 6;
  const int wr = w >> 1, wc = w & 1;
  const int row0 = blockIdx.x * 128;
  const int quad = lane >> 4;
  const int l16 = lane & 15;

  f32x4 acc[4][4];
#pragma unroll
  for (int i = 0; i < 4; i++)
#pragma unroll
    for (int j = 0; j < 4; j++) acc[i][j] = f32x4{0.f, 0.f, 0.f, 0.f};

  for (int k0 = 0; k0 < K; k0 += 32) {
#pragma unroll
    for (int rpt = 0; rpt < 2; rpt++) {
      int seg = t + rpt * 256;                  // 0..511: 128 rows x 4 segs of 8 f32
      int row = seg >> 2, ks = seg & 3;
      int grow = row0 + row; if (grow >= Nrows) grow = Nrows - 1;
      const float* gp = A + (size_t)grow * K + k0 + ks * 8;
      float4 f0 = *reinterpret_cast<const float4*>(gp);
      float4 f1 = *reinterpret_cast<const float4*>(gp + 4);
      uint4 pk;
      pk.x = pkh2(f0.x, f0.y); pk.y = pkh2(f0.z, f0.w);
      pk.z = pkh2(f1.x, f1.y); pk.w = pkh2(f1.z, f1.w);
      *reinterpret_cast<uint4*>(&lA[seg * 8]) = pk;
    }
    __syncthreads();

    f16x8 af[4], bfr[4];
#pragma unroll
    for (int i = 0; i < 4; i++) {
      int r = wr * 64 + i * 16 + l16;
      af[i] = *reinterpret_cast<const f16x8*>(&lA[r * 32 + quad * 8]);
    }
#pragma unroll
    for (int j = 0; j < 4; j++) {
      int c = wc * 64 + j * 16 + l16;
      bfr[j] = *reinterpret_cast<const f16x8*>(Bt + (size_t)c * K + k0 + quad * 8);
    }
    __syncthreads();

#pragma unroll
    for (int i = 0; i < 4; i++)
#pragma unroll
      for (int j = 0; j < 4; j++)
        acc[i][j] = __builtin_amdgcn_mfma_f32_16x16x32_f16(af[i], bfr[j], acc[i][j], 0, 0, 0);
  }

  // epilogue: C/D layout col=lane&15, row=quad*4+reg
#pragma unroll
  for (int i = 0; i < 4; i++) {
    int rbase = row0 + wr * 64 + i * 16 + quad * 4;
#pragma unroll
    for (int j = 0; j < 4; j++) {
      int c = wc * 64 + j * 16 + l16;
      float bv = bias[c];
#pragma unroll
      for (int r = 0; r < 4; r++) {
        int grow = rbase + r;
        if (grow < Nrows) Out[(size_t)grow * 128 + c] = f2h(acc[i][j][r] + bv);
      }
    }
  }
}

// ---------------- fused GCN layer: Hout = relu( Agg(Hin) @ W + b ) ----------------
// Agg(H)_i = sum_{e: dst=i} wn[e]*H[col[e]] + dinv_i^2 * H_i   (aggregate-first == reference by linearity)
// 512 threads / 8 waves; phase 1 gathers 128 rows into LDS (f16, stride 136); phase 2 MFMA vs W from global.

__global__ __launch_bounds__(512) void gcn_layer_kernel(
    const u16* __restrict__ Hin, const int* __restrict__ offs,
    const int* __restrict__ col, const float* __restrict__ wn,
    const float* __restrict__ dinv, const f16* __restrict__ Wt,   // Wt[128][128] = [n][k]
    const float* __restrict__ bias, u16* __restrict__ Hout, int N)
{
  __shared__ u16 lA[128 * 136];        // +8 f16 pad per row: breaks pow2 bank stride
  const int t = threadIdx.x;
  const int lane = t & 63;
  const int w = t >> 6;                // 0..7
  const int row0 = blockIdx.x * 128;
  const u32* h32 = (const u32*)Hin;
  u32* lA32 = (u32*)lA;

  // phase 1: aggregation, one wave per row, 16 rows per wave
  for (int r = w; r < 128; r += 8) {
    int i = row0 + r;
    float ax = 0.f, ay = 0.f;
    if (i < N) {
      float di = dinv[i];
      float sw = di * di;
      u32 us = h32[(size_t)i * 64 + lane];
      ax = sw * h2f_lo(us); ay = sw * h2f_hi(us);
      int e = offs[i + 1];
      int p = offs[i];
      for (; p + 4 <= e; p += 4) {
        int j0 = col[p], j1 = col[p + 1], j2 = col[p + 2], j3 = col[p + 3];
        float w0 = wn[p], w1 = wn[p + 1], w2 = wn[p + 2], w3 = wn[p + 3];
        u32 u0 = h32[(size_t)j0 * 64 + lane];
        u32 u1 = h32[(size_t)j1 * 64 + lane];
        u32 u2 = h32[(size_t)j2 * 64 + lane];
        u32 u3 = h32[(size_t)j3 * 64 + lane];
        ax += w0 * h2f_lo(u0); ay += w0 * h2f_hi(u0);
        ax += w1 * h2f_lo(u1); ay += w1 * h2f_hi(u1);
        ax += w2 * h2f_lo(u2); ay += w2 * h2f_hi(u2);
        ax += w3 * h2f_lo(u3); ay += w3 * h2f_hi(u3);
      }
      for (; p < e; p++) {
        int j = col[p]; float wv = wn[p];
        u32 uu = h32[(size_t)j * 64 + lane];
        ax += wv * h2f_lo(uu); ay += wv * h2f_hi(uu);
      }
    }
    lA32[r * 68 + lane] = pkh2(ax, ay);
  }
  __syncthreads();

  // phase 2: GEMM — wave w computes rows [w*16, w*16+16) x cols [0,128)
  const int l16 = lane & 15, quad = lane >> 4;
  f32x4 acc[8];
#pragma unroll
  for (int j = 0; j < 8; j++) acc[j] = f32x4{0.f, 0.f, 0.f, 0.f};

#pragma unroll
  for (int k0 = 0; k0 < 128; k0 += 32) {
    f16x8 af = *reinterpret_cast<const f16x8*>(&lA[(w * 16 + l16) * 136 + k0 + quad * 8]);
#pragma unroll
    for (int j = 0; j < 8; j++) {
      f16x8 bf = *reinterpret_cast<const f16x8*>(Wt + (size_t)(j * 16 + l16) * 128 + k0 + quad * 8);
      acc[j] = __builtin_amdgcn_mfma_f32_16x16x32_f16(af, bf, acc[j], 0, 0, 0);
    }
  }

  // phase 3: bias + relu + store (C/D: col=l16, row=quad*4+reg within the 16x16 tile)
#pragma unroll
  for (int j = 0; j < 8; j++) {
    int c = j * 16 + l16;
    float bv = bias[c];
#pragma unroll
    for (int r = 0; r < 4; r++) {
      int grow = row0 + w * 16 + quad * 4 + r;
      if (grow < N) Hout[(size_t)grow * 128 + c] = f2h(fmaxf(acc[j][r] + bv, 0.f));
    }
  }
}

// ---------------- classifier: logits[N][8] = concat(lm,out)[N][256] @ Wc[256][8] + bc ----------

__global__ __launch_bounds__(256) void classifier_kernel(
    const u16* __restrict__ lm, const u16* __restrict__ feat,
    const float* __restrict__ Wc, const float* __restrict__ bc,
    float* __restrict__ out, int N)
{
  __shared__ float sW[256 * 8];
  __shared__ u16 sF[32 * 264];
  int t = threadIdx.x;
#pragma unroll
  for (int r = 0; r < 8; r++) sW[t + r * 256] = Wc[t + r * 256];
  int n0 = blockIdx.x * 32;
  u32* sF32 = (u32*)sF;
#pragma unroll
  for (int r = 0; r < 8; r++) {
    int idx = t + r * 256;
    int n = idx >> 6, cpos = idx & 63;
    int gn = n0 + n; if (gn >= N) gn = N - 1;
    sF32[n * 132 + cpos]      = ((const u32*)lm)[(size_t)gn * 64 + cpos];
    sF32[n * 132 + 64 + cpos] = ((const u32*)feat)[(size_t)gn * 64 + cpos];
  }
  __syncthreads();
  int n = t >> 3, c = t & 7;
  int gn = n0 + n;
  const f16* sFh = (const f16*)sF;
  float sum = bc[c];
#pragma unroll 16
  for (int k = 0; k < 256; k++)
    sum += (float)sFh[n * 264 + k] * sW[k * 8 + c];
  if (gn < N) out[(size_t)gn * 8 + c] = sum;
}

// ---------------- launcher ----------------

static inline char* bump(char*& p, size_t bytes) {
  char* r = p;
  p += (bytes + 255) & ~(size_t)255;
  return r;
}

extern "C" void kernel_launch(void* const* d_in, const int* in_sizes, int n_in,
                              void* d_out, int out_size, void* d_ws, size_t ws_size,
                              hipStream_t stream) {
  const float* X   = (const float*)d_in[0];   // [N][1024]
  const int*   EI  = (const int*)  d_in[1];   // [2][E]
  const float* Wlm = (const float*)d_in[2];   // [1024][128]
  const float* blm = (const float*)d_in[3];   // [128]
  const float* Wg  = (const float*)d_in[4];   // [L][128][128]
  const float* bg  = (const float*)d_in[5];   // [L][128]
  const float* Wc  = (const float*)d_in[6];   // [256][8]
  const float* bc  = (const float*)d_in[7];   // [8]
  float* out = (float*)d_out;

  const int N = in_sizes[0] / 1024;
  const int E = in_sizes[1] / 2;
  const int L = in_sizes[4] / (128 * 128);

  char* wp = (char*)d_ws;
  int*   counts  = (int*)  bump(wp, (size_t)N * 4);
  int*   cursor  = (int*)  bump(wp, (size_t)N * 4);
  int*   offs    = (int*)  bump(wp, (size_t)(N + 1) * 4);
  float* dinv    = (float*)bump(wp, (size_t)N * 4);
  int*   partials= (int*)  bump(wp, 1024 * 4);
  int*   colA    = (int*)  bump(wp, (size_t)E * 4);
  float* wnA     = (float*)bump(wp, (size_t)E * 4);
  f16*   WlmT    = (f16*)  bump(wp, (size_t)1024 * 128 * 2);
  f16*   WgT     = (f16*)  bump(wp, (size_t)L * 128 * 128 * 2);
  u16*   lmB     = (u16*)  bump(wp, (size_t)N * 128 * 2);
  u16*   fA      = (u16*)  bump(wp, (size_t)N * 128 * 2);
  u16*   fB      = (u16*)  bump(wp, (size_t)N * 128 * 2);

  (void)hipMemsetAsync(counts, 0, (size_t)N * 4, stream);
  (void)hipMemsetAsync(cursor, 0, (size_t)N * 4, stream);

  const int* srcp = EI;
  const int* dstp = EI + E;

  count_kernel<<<(E + 255) / 256, 256, 0, stream>>>(dstp, counts, E);
  dinv_kernel<<<(N + 255) / 256, 256, 0, stream>>>(counts, dinv, N);

  int NB = (N + 1023) / 1024;
  scan_partial<<<NB, 256, 0, stream>>>(counts, partials, N);
  scan_partials_excl<<<1, 256, 0, stream>>>(partials, NB, offs, N, E);
  scan_final<<<NB, 256, 0, stream>>>(counts, partials, offs, N);
  fill_kernel<<<(E + 255) / 256, 256, 0, stream>>>(srcp, dstp, offs, cursor, dinv, colA, wnA, E);

  int PT = 1024 * 128 + L * 128 * 128;
  prep_weights<<<(PT + 255) / 256, 256, 0, stream>>>(Wlm, Wg, WlmT, WgT, PT);

  int GB = (N + 127) / 128;
  lm_gemm_kernel<1024><<<GB, 256, 0, stream>>>(X, WlmT, blm, lmB, N);

  const u16* cur = lmB;
  u16* bufs[3] = {fA, fB, fA};          // l1: lm->fA, l2: fA->fB, l3: fB->fA
  for (int l = 0; l < L; l++) {
    u16* dst = bufs[l % 3];
    gcn_layer_kernel<<<GB, 512, 0, stream>>>(cur, offs, colA, wnA, dinv,
                                             WgT + (size_t)l * 16384, bg + (size_t)l * 128, dst, N);
    cur = dst;
  }

  classifier_kernel<<<(N + 31) / 32, 256, 0, stream>>>(lmB, cur, Wc, bc, out, N);
}

// Round 4
// 994.627 us; speedup vs baseline: 1.1758x; 1.1758x over previous
//
#include <hip/hip_runtime.h>

// LMFreezeConcatModel: lm = X@W_lm+b ; 3x GCNConv(sym-norm, self-loops) ; concat -> W_cls.
// R4: R1 pipeline structure (separate GEMM + one-wave-per-row aggregate; LDS-staged A and B)
//     + f16 datapath with v_cvt_pkrtz packing + LDS row-stride pad 32->40 u16 (2-way, free).

typedef unsigned short u16;
typedef unsigned int   u32;
typedef _Float16 f16;
typedef f16 f16x8 __attribute__((ext_vector_type(8)));
typedef f16 f16x2 __attribute__((ext_vector_type(2)));
typedef __fp16 fp16x2_storage __attribute__((ext_vector_type(2)));
typedef float f32x4 __attribute__((ext_vector_type(4)));

__device__ __forceinline__ u32 pkh2(float a, float b) {
  fp16x2_storage h = __builtin_amdgcn_cvt_pkrtz(a, b);   // 1 VALU instr per 2 elems
  return __builtin_bit_cast(u32, h);
}
__device__ __forceinline__ float h2f_lo(u32 u) { return (float)__builtin_bit_cast(f16x2, u)[0]; }
__device__ __forceinline__ float h2f_hi(u32 u) { return (float)__builtin_bit_cast(f16x2, u)[1]; }
__device__ __forceinline__ u16 f2h(float f) { return __builtin_bit_cast(u16, (f16)f); }

// ---------------- degree / CSR build ----------------

__global__ void count_kernel(const int* __restrict__ dst, int* __restrict__ counts, int E) {
  int e = blockIdx.x * 256 + threadIdx.x;
  if (e < E) atomicAdd(&counts[dst[e]], 1);
}

__global__ void dinv_kernel(const int* __restrict__ counts, float* __restrict__ dinv, int N) {
  int i = blockIdx.x * 256 + threadIdx.x;
  if (i < N) dinv[i] = rsqrtf((float)(counts[i] + 1));   // +1 self-loop
}

__global__ void scan_partial(const int* __restrict__ counts, int* __restrict__ partials, int N) {
  __shared__ int sdata[256];
  int t = threadIdx.x;
  int base = blockIdx.x * 1024 + t * 4;
  int s = 0;
#pragma unroll
  for (int i = 0; i < 4; i++) { int idx = base + i; if (idx < N) s += counts[idx]; }
  sdata[t] = s; __syncthreads();
  for (int off = 128; off > 0; off >>= 1) {
    if (t < off) sdata[t] += sdata[t + off];
    __syncthreads();
  }
  if (t == 0) partials[blockIdx.x] = sdata[0];
}

__global__ void scan_partials_excl(int* __restrict__ partials, int NB,
                                   int* __restrict__ offsets, int N, int E) {
  __shared__ int sdata[256];
  int t = threadIdx.x;
  int v = (t < NB) ? partials[t] : 0;
  sdata[t] = v; __syncthreads();
  int val = v;
  for (int off = 1; off < 256; off <<= 1) {
    int add = (t >= off) ? sdata[t - off] : 0;
    __syncthreads();
    val += add; sdata[t] = val;
    __syncthreads();
  }
  if (t < NB) partials[t] = val - v;
  if (t == 0) offsets[N] = E;
}

__global__ void scan_final(const int* __restrict__ counts, const int* __restrict__ partials,
                           int* __restrict__ offsets, int N) {
  __shared__ int sdata[256];
  int t = threadIdx.x;
  int base = blockIdx.x * 1024 + t * 4;
  int v[4]; int tsum = 0;
#pragma unroll
  for (int i = 0; i < 4; i++) { int idx = base + i; v[i] = (idx < N) ? counts[idx] : 0; tsum += v[i]; }
  sdata[t] = tsum; __syncthreads();
  int val = tsum;
  for (int off = 1; off < 256; off <<= 1) {
    int add = (t >= off) ? sdata[t - off] : 0;
    __syncthreads();
    val += add; sdata[t] = val;
    __syncthreads();
  }
  int run = partials[blockIdx.x] + val - tsum;
#pragma unroll
  for (int i = 0; i < 4; i++) { int idx = base + i; if (idx < N) offsets[idx] = run; run += v[i]; }
}

__global__ void fill_kernel(const int* __restrict__ src, const int* __restrict__ dst,
                            const int* __restrict__ offsets, int* __restrict__ cursor,
                            const float* __restrict__ dinv,
                            int* __restrict__ col, float* __restrict__ wn, int E) {
  int e = blockIdx.x * 256 + threadIdx.x;
  if (e < E) {
    int d = dst[e], s = src[e];
    int p = offsets[d] + atomicAdd(&cursor[d], 1);
    col[p] = s;
    wn[p] = dinv[s] * dinv[d];
  }
}

// ---------------- weight prep: f32 -> f16, transposed to [col][k] ----------------

__global__ void prep_weights(const float* __restrict__ Wlm, const float* __restrict__ Wg,
                             f16* __restrict__ WlmT, f16* __restrict__ WgT, int total) {
  int idx = blockIdx.x * 256 + threadIdx.x;
  if (idx < 1024 * 128) {
    int k = idx >> 7, c = idx & 127;
    WlmT[c * 1024 + k] = (f16)Wlm[idx];
  } else if (idx < total) {
    int r = idx - 1024 * 128;
    int l = r >> 14; int rr = r & 16383;
    int k = rr >> 7, c = rr & 127;
    WgT[l * 16384 + c * 128 + k] = (f16)Wg[r];
  }
}

// ---------------- MFMA GEMM: Out[N][128] = A[N][K] @ B[K][128] (+bias) ----------------
// Bt = [128][K] f16. BM=128, BN=128, BK=32, 4 waves (64x64 each). LDS rows padded to 40 u16.

template<int K, bool A_IS_F32, bool ADD_BIAS>
__global__ __launch_bounds__(256) void gemm_kernel(
    const void* __restrict__ Aptr, const f16* __restrict__ Bt,
    const float* __restrict__ bias, u16* __restrict__ Out, int Nrows)
{
  __shared__ u16 lA[128 * 40];         // stride 40 u16 = 20 dwords -> 2-way bank alias (free)
  __shared__ u16 lB[128 * 40];
  const int t = threadIdx.x;
  const int lane = t & 63;
  const int w = t >> 6;
  const int wr = w >> 1, wc = w & 1;
  const int row0 = blockIdx.x * 128;
  const int quad = lane >> 4;
  const int l16 = lane & 15;

  f32x4 acc[4][4];
#pragma unroll
  for (int i = 0; i < 4; i++)
#pragma unroll
    for (int j = 0; j < 4; j++) acc[i][j] = f32x4{0.f, 0.f, 0.f, 0.f};

  for (int k0 = 0; k0 < K; k0 += 32) {
    // --- stage A tile [128][32] ---
    if (A_IS_F32) {
      const float* A = (const float*)Aptr;
#pragma unroll
      for (int rpt = 0; rpt < 2; rpt++) {
        int seg = t + rpt * 256;                  // 0..511: 128 rows x 4 segs of 8
        int row = seg >> 2, ks = seg & 3;
        int grow = row0 + row; if (grow >= Nrows) grow = Nrows - 1;
        const float* gp = A + (size_t)grow * K + k0 + ks * 8;
        float4 f0 = *reinterpret_cast<const float4*>(gp);
        float4 f1 = *reinterpret_cast<const float4*>(gp + 4);
        uint4 pk;
        pk.x = pkh2(f0.x, f0.y); pk.y = pkh2(f0.z, f0.w);
        pk.z = pkh2(f1.x, f1.y); pk.w = pkh2(f1.z, f1.w);
        *reinterpret_cast<uint4*>(&lA[row * 40 + ks * 8]) = pk;
      }
    } else {
      const u16* A = (const u16*)Aptr;
#pragma unroll
      for (int rpt = 0; rpt < 2; rpt++) {
        int seg = t + rpt * 256;
        int row = seg >> 2, ks = seg & 3;
        int grow = row0 + row; if (grow >= Nrows) grow = Nrows - 1;
        const u16* gp = A + (size_t)grow * K + k0 + ks * 8;
        *reinterpret_cast<uint4*>(&lA[row * 40 + ks * 8]) = *reinterpret_cast<const uint4*>(gp);
      }
    }
    // --- stage B tile [128 cols][32] from Bt[128][K] ---
#pragma unroll
    for (int rpt = 0; rpt < 2; rpt++) {
      int seg = t + rpt * 256;
      int c = seg >> 2, ks = seg & 3;
      const f16* gp = Bt + (size_t)c * K + k0 + ks * 8;
      *reinterpret_cast<uint4*>(&lB[c * 40 + ks * 8]) = *reinterpret_cast<const uint4*>(gp);
    }
    __syncthreads();

    f16x8 af[4], bfr[4];
#pragma unroll
    for (int i = 0; i < 4; i++) {
      int r = wr * 64 + i * 16 + l16;
      af[i] = *reinterpret_cast<const f16x8*>(&lA[r * 40 + quad * 8]);
    }
#pragma unroll
    for (int j = 0; j < 4; j++) {
      int c = wc * 64 + j * 16 + l16;
      bfr[j] = *reinterpret_cast<const f16x8*>(&lB[c * 40 + quad * 8]);
    }
    __syncthreads();

#pragma unroll
    for (int i = 0; i < 4; i++)
#pragma unroll
      for (int j = 0; j < 4; j++)
        acc[i][j] = __builtin_amdgcn_mfma_f32_16x16x32_f16(af[i], bfr[j], acc[i][j], 0, 0, 0);
  }

  // epilogue: C/D layout col=lane&15, row=quad*4+reg
#pragma unroll
  for (int i = 0; i < 4; i++) {
    int rbase = row0 + wr * 64 + i * 16 + quad * 4;
#pragma unroll
    for (int j = 0; j < 4; j++) {
      int c = wc * 64 + j * 16 + l16;
      float bv = ADD_BIAS ? bias[c] : 0.f;
#pragma unroll
      for (int r = 0; r < 4; r++) {
        int grow = rbase + r;
        if (grow < Nrows) Out[(size_t)grow * 128 + c] = f2h(acc[i][j][r] + bv);
      }
    }
  }
}

// ---------------- aggregation: out[i] = relu( sum_{e:dst=i} wn[e]*h[col[e]] + dinv_i^2*h[i] + b ) ----
// one wave per dst row (max TLP for the latency-bound gather); lane covers 2 f16 feats.

__global__ __launch_bounds__(256) void aggregate_kernel(
    const u16* __restrict__ h, const int* __restrict__ offsets,
    const int* __restrict__ col, const float* __restrict__ wn,
    const float* __restrict__ dinv, const float* __restrict__ bias,
    u16* __restrict__ outf, int N)
{
  int w = threadIdx.x >> 6;
  int lane = threadIdx.x & 63;
  int i = blockIdx.x * 4 + w;
  if (i >= N) return;
  const u32* h32 = (const u32*)h;
  float di = dinv[i];
  float sw = di * di;
  u32 us = h32[(size_t)i * 64 + lane];
  float ax = sw * h2f_lo(us);
  float ay = sw * h2f_hi(us);
  int s = offsets[i], e = offsets[i + 1];
  int p = s;
  for (; p + 4 <= e; p += 4) {          // batch-4 memory-level parallelism
    int j0 = col[p], j1 = col[p + 1], j2 = col[p + 2], j3 = col[p + 3];
    float w0 = wn[p], w1 = wn[p + 1], w2 = wn[p + 2], w3 = wn[p + 3];
    u32 u0 = h32[(size_t)j0 * 64 + lane];
    u32 u1 = h32[(size_t)j1 * 64 + lane];
    u32 u2 = h32[(size_t)j2 * 64 + lane];
    u32 u3 = h32[(size_t)j3 * 64 + lane];
    ax += w0 * h2f_lo(u0); ay += w0 * h2f_hi(u0);
    ax += w1 * h2f_lo(u1); ay += w1 * h2f_hi(u1);
    ax += w2 * h2f_lo(u2); ay += w2 * h2f_hi(u2);
    ax += w3 * h2f_lo(u3); ay += w3 * h2f_hi(u3);
  }
  for (; p < e; p++) {
    int j = col[p]; float wv = wn[p];
    u32 uu = h32[(size_t)j * 64 + lane];
    ax += wv * h2f_lo(uu); ay += wv * h2f_hi(uu);
  }
  ax = fmaxf(ax + bias[lane * 2], 0.f);
  ay = fmaxf(ay + bias[lane * 2 + 1], 0.f);
  ((u32*)outf)[(size_t)i * 64 + lane] = pkh2(ax, ay);
}

// ---------------- classifier: logits[N][8] = concat(lm,out)[N][256] @ Wc[256][8] + bc ----------

__global__ __launch_bounds__(256) void classifier_kernel(
    const u16* __restrict__ lm, const u16* __restrict__ feat,
    const float* __restrict__ Wc, const float* __restrict__ bc,
    float* __restrict__ out, int N)
{
  __shared__ float sW[256 * 8];
  __shared__ u16 sF[32 * 264];
  int t = threadIdx.x;
#pragma unroll
  for (int r = 0; r < 8; r++) sW[t + r * 256] = Wc[t + r * 256];
  int n0 = blockIdx.x * 32;
  u32* sF32 = (u32*)sF;
#pragma unroll
  for (int r = 0; r < 8; r++) {
    int idx = t + r * 256;
    int n = idx >> 6, cpos = idx & 63;
    int gn = n0 + n; if (gn >= N) gn = N - 1;
    sF32[n * 132 + cpos]      = ((const u32*)lm)[(size_t)gn * 64 + cpos];
    sF32[n * 132 + 64 + cpos] = ((const u32*)feat)[(size_t)gn * 64 + cpos];
  }
  __syncthreads();
  int n = t >> 3, c = t & 7;
  int gn = n0 + n;
  const f16* sFh = (const f16*)sF;
  float sum = bc[c];
#pragma unroll 16
  for (int k = 0; k < 256; k++)
    sum += (float)sFh[n * 264 + k] * sW[k * 8 + c];
  if (gn < N) out[(size_t)gn * 8 + c] = sum;
}

// ---------------- launcher ----------------

static inline char* bump(char*& p, size_t bytes) {
  char* r = p;
  p += (bytes + 255) & ~(size_t)255;
  return r;
}

extern "C" void kernel_launch(void* const* d_in, const int* in_sizes, int n_in,
                              void* d_out, int out_size, void* d_ws, size_t ws_size,
                              hipStream_t stream) {
  const float* X   = (const float*)d_in[0];   // [N][1024]
  const int*   EI  = (const int*)  d_in[1];   // [2][E]
  const float* Wlm = (const float*)d_in[2];   // [1024][128]
  const float* blm = (const float*)d_in[3];   // [128]
  const float* Wg  = (const float*)d_in[4];   // [L][128][128]
  const float* bg  = (const float*)d_in[5];   // [L][128]
  const float* Wc  = (const float*)d_in[6];   // [256][8]
  const float* bc  = (const float*)d_in[7];   // [8]
  float* out = (float*)d_out;

  const int N = in_sizes[0] / 1024;
  const int E = in_sizes[1] / 2;
  const int L = in_sizes[4] / (128 * 128);

  char* wp = (char*)d_ws;
  int*   counts  = (int*)  bump(wp, (size_t)N * 4);
  int*   cursor  = (int*)  bump(wp, (size_t)N * 4);
  int*   offs    = (int*)  bump(wp, (size_t)(N + 1) * 4);
  float* dinv    = (float*)bump(wp, (size_t)N * 4);
  int*   partials= (int*)  bump(wp, 1024 * 4);
  int*   colA    = (int*)  bump(wp, (size_t)E * 4);
  float* wnA     = (float*)bump(wp, (size_t)E * 4);
  f16*   WlmT    = (f16*)  bump(wp, (size_t)1024 * 128 * 2);
  f16*   WgT     = (f16*)  bump(wp, (size_t)L * 128 * 128 * 2);
  u16*   lmB     = (u16*)  bump(wp, (size_t)N * 128 * 2);
  u16*   hB      = (u16*)  bump(wp, (size_t)N * 128 * 2);
  u16*   fA      = (u16*)  bump(wp, (size_t)N * 128 * 2);
  u16*   fB      = (u16*)  bump(wp, (size_t)N * 128 * 2);

  (void)hipMemsetAsync(counts, 0, (size_t)N * 4, stream);
  (void)hipMemsetAsync(cursor, 0, (size_t)N * 4, stream);

  const int* srcp = EI;
  const int* dstp = EI + E;

  count_kernel<<<(E + 255) / 256, 256, 0, stream>>>(dstp, counts, E);
  dinv_kernel<<<(N + 255) / 256, 256, 0, stream>>>(counts, dinv, N);

  int NB = (N + 1023) / 1024;
  scan_partial<<<NB, 256, 0, stream>>>(counts, partials, N);
  scan_partials_excl<<<1, 256, 0, stream>>>(partials, NB, offs, N, E);
  scan_final<<<NB, 256, 0, stream>>>(counts, partials, offs, N);
  fill_kernel<<<(E + 255) / 256, 256, 0, stream>>>(srcp, dstp, offs, cursor, dinv, colA, wnA, E);

  int PT = 1024 * 128 + L * 128 * 128;
  prep_weights<<<(PT + 255) / 256, 256, 0, stream>>>(Wlm, Wg, WlmT, WgT, PT);

  int GB = (N + 127) / 128;
  gemm_kernel<1024, true, true><<<GB, 256, 0, stream>>>(X, WlmT, blm, lmB, N);

  const u16* cur = lmB;
  u16* bufs[3] = {fA, fB, fA};
  for (int l = 0; l < L; l++) {
    gemm_kernel<128, false, false><<<GB, 256, 0, stream>>>(cur, WgT + (size_t)l * 16384, nullptr, hB, N);
    u16* dst = bufs[l % 3];
    aggregate_kernel<<<(N + 3) / 4, 256, 0, stream>>>(hB, offs, colA, wnA, dinv, bg + (size_t)l * 128, dst, N);
    cur = dst;
  }

  classifier_kernel<<<(N + 31) / 32, 256, 0, stream>>>(lmB, cur, Wc, bc, out, N);
}